// Round 1
// baseline (705.107 us; speedup 1.0000x reference)
//
#include <hip/hip_runtime.h>

#define NT 4096          // time samples per column
#define NCOL 4096        // 512 traces * 8 channels
#define SORT_THREADS 256 // threads per array sort
#define BLOCK 512

__global__ __launch_bounds__(512) void wass_kernel(const float* __restrict__ pred,
                                                   const float* __restrict__ obs,
                                                   float* __restrict__ out) {
    __shared__ float sp[NT];
    __shared__ float so[NT];
    __shared__ float red[BLOCK / 64];

    const int bid = blockIdx.x;
    // XCD swizzle: assuming round-robin bid->XCD, give each XCD a contiguous
    // 512-column band so 64B lines (16 adjacent columns) are reused in its L2.
    const int col = (bid & 7) * 512 + (bid >> 3);

    const int ttid = threadIdx.x;
    const int arr  = ttid >> 8;   // 0 => pred/sp, 1 => obs/so (wave-uniform)
    const int tid  = ttid & 255;
    float* a = arr ? so : sp;
    const float* __restrict__ src = arr ? obs : pred;

    // Load one column (strided by 16KB; L2/L3 absorb line reuse across columns)
    #pragma unroll
    for (int t = tid; t < NT; t += SORT_THREADS) {
        a[t] = src[(size_t)t * NCOL + col];
    }
    __syncthreads();

    // Bitonic sort ascending, 256 threads per array, 8 compare-exchanges each/stage
    for (int k = 2; k <= NT; k <<= 1) {
        for (int j = k >> 1; j > 0; j >>= 1) {
            #pragma unroll
            for (int p = 0; p < NT / 2 / SORT_THREADS; ++p) {
                const int pidx = tid + p * SORT_THREADS;     // [0, 2048)
                const int i    = ((pidx & ~(j - 1)) << 1) | (pidx & (j - 1));
                const int ip   = i | j;
                const float x = a[i];
                const float y = a[ip];
                const bool up = ((i & k) == 0);
                const float lo = fminf(x, y);
                const float hi = fmaxf(x, y);
                a[i]  = up ? lo : hi;
                a[ip] = up ? hi : lo;
            }
            __syncthreads();
        }
    }

    // Sum |sp[i] - so[i]| over the column with all 512 threads
    float s = 0.0f;
    #pragma unroll
    for (int i = ttid; i < NT; i += BLOCK) {
        s += fabsf(sp[i] - so[i]);
    }
    // wave64 reduce
    #pragma unroll
    for (int off = 32; off > 0; off >>= 1) {
        s += __shfl_down(s, off, 64);
    }
    if ((ttid & 63) == 0) red[ttid >> 6] = s;
    __syncthreads();
    if (ttid == 0) {
        float tot = 0.0f;
        #pragma unroll
        for (int w = 0; w < BLOCK / 64; ++w) tot += red[w];
        // mean over NT, then mean over NCOL columns
        atomicAdd(out, tot * (1.0f / ((float)NT * (float)NCOL)));
    }
}

extern "C" void kernel_launch(void* const* d_in, const int* in_sizes, int n_in,
                              void* d_out, int out_size, void* d_ws, size_t ws_size,
                              hipStream_t stream) {
    const float* pred = (const float*)d_in[0];
    const float* obs  = (const float*)d_in[1];
    float* out = (float*)d_out;
    // d_out is poisoned to 0xAA before every timed launch; we accumulate with
    // atomics, so zero it first (async memset is graph-capture legal).
    hipMemsetAsync(out, 0, sizeof(float), stream);
    wass_kernel<<<NCOL, BLOCK, 0, stream>>>(pred, obs, out);
}

// Round 2
// 342.301 us; speedup vs baseline: 2.0599x; 2.0599x over previous
//
#include <hip/hip_runtime.h>

#define NT 4096          // time samples per column
#define NCOL 4096        // 512 traces * 8 channels
#define EPT 16           // elements per thread (one chunk)
#define SORT_T 256       // threads per array
#define BLOCK 512
#define CH_STRIDE 17     // padded LDS chunk stride (words) -> conflict-free b32

__device__ __forceinline__ void ce(float& a, float& b, bool up) {
    const float lo = fminf(a, b);
    const float hi = fmaxf(a, b);
    a = up ? lo : hi;
    b = up ? hi : lo;
}

__global__ __launch_bounds__(512) void wass_kernel(const float* __restrict__ pred,
                                                   const float* __restrict__ obs,
                                                   float* __restrict__ out) {
    __shared__ float lsA[SORT_T * CH_STRIDE];   // pred half
    __shared__ float lsB[SORT_T * CH_STRIDE];   // obs half
    __shared__ float red[BLOCK / 64];

    const int bid = blockIdx.x;
    // XCD swizzle: adjacent-resident blocks handle adjacent columns -> 64B-line
    // reuse (16 cols/line) within each XCD's L2.
    const int col = (bid & 7) * 512 + (bid >> 3);

    const int t   = threadIdx.x;
    const int arr = t >> 8;          // 0 = pred, 1 = obs (wave-uniform)
    const int c   = t & 255;         // chunk index within the array
    const float* __restrict__ src = arr ? obs : pred;
    float* ls = arr ? lsB : lsA;     // wave-uniform pointer

    const int gbase = c * EPT;       // first global element index of my chunk

    // ---- load 16 elements of my column chunk (gather, L2/L3 mostly) ----
    float x[EPT];
    #pragma unroll
    for (int e = 0; e < EPT; ++e)
        x[e] = src[(size_t)(gbase + e) * NCOL + col];

    // ---- phase 1: k = 2..16, all pairs intra-thread (registers only) ----
    #pragma unroll
    for (int k = 2; k <= 16; k <<= 1) {
        #pragma unroll
        for (int j = k >> 1; j > 0; j >>= 1) {
            #pragma unroll
            for (int e = 0; e < EPT; ++e) {
                if ((e & j) == 0) {
                    const bool up = (((gbase + e) & k) == 0);
                    ce(x[e], x[e | j], up);
                }
            }
        }
    }

    // ---- phase 2: k = 32..4096 ----
    #pragma unroll
    for (int k = 32; k <= NT; k <<= 1) {
        const bool d_up = ((gbase & k) == 0);       // lane-uniform direction
        #pragma unroll
        for (int j = k >> 1; j >= EPT; j >>= 1) {
            const int m = j >> 4;                   // chunk xor distance
            const bool keep_min = (((c & m) == 0) == d_up);
            if (m <= 32) {
                // partner chunk is in the same wave: ds_bpermute, no barriers
                #pragma unroll
                for (int e = 0; e < EPT; ++e) {
                    const float y = __shfl_xor(x[e], m, 64);
                    x[e] = keep_min ? fminf(x[e], y) : fmaxf(x[e], y);
                }
            } else {
                // cross-wave (j = 1024, 2048): LDS round-trip
                #pragma unroll
                for (int e = 0; e < EPT; ++e)
                    ls[c * CH_STRIDE + e] = x[e];
                __syncthreads();
                const int pc = c ^ m;
                #pragma unroll
                for (int e = 0; e < EPT; ++e) {
                    const float y = ls[pc * CH_STRIDE + e];
                    x[e] = keep_min ? fminf(x[e], y) : fmaxf(x[e], y);
                }
                __syncthreads();
            }
        }
        // local tail j = 8..1 (intra-thread); direction is d_up for all e
        #pragma unroll
        for (int j = 8; j > 0; j >>= 1) {
            #pragma unroll
            for (int e = 0; e < EPT; ++e) {
                if ((e & j) == 0) ce(x[e], x[e | j], d_up);
            }
        }
    }

    // ---- epilogue: both sorted arrays -> LDS, abs-diff, block reduce ----
    #pragma unroll
    for (int e = 0; e < EPT; ++e)
        ls[c * CH_STRIDE + e] = x[e];
    __syncthreads();

    float s = 0.0f;
    #pragma unroll
    for (int q = 0; q < NT / BLOCK; ++q) {
        const int g = t * (NT / BLOCK) + q;
        const int w = (g >> 4) * CH_STRIDE + (g & 15);
        s += fabsf(lsA[w] - lsB[w]);
    }
    #pragma unroll
    for (int off = 32; off > 0; off >>= 1)
        s += __shfl_down(s, off, 64);
    if ((t & 63) == 0) red[t >> 6] = s;
    __syncthreads();
    if (t == 0) {
        float tot = 0.0f;
        #pragma unroll
        for (int w = 0; w < BLOCK / 64; ++w) tot += red[w];
        atomicAdd(out, tot * (1.0f / ((float)NT * (float)NCOL)));
    }
}

extern "C" void kernel_launch(void* const* d_in, const int* in_sizes, int n_in,
                              void* d_out, int out_size, void* d_ws, size_t ws_size,
                              hipStream_t stream) {
    const float* pred = (const float*)d_in[0];
    const float* obs  = (const float*)d_in[1];
    float* out = (float*)d_out;
    // d_out is poisoned to 0xAA before every timed launch; zero it (async, capture-legal).
    hipMemsetAsync(out, 0, sizeof(float), stream);
    wass_kernel<<<NCOL, BLOCK, 0, stream>>>(pred, obs, out);
}

// Round 3
// 317.122 us; speedup vs baseline: 2.2235x; 1.0794x over previous
//
#include <hip/hip_runtime.h>

#define NT 4096          // time samples per column
#define NCOL 4096        // 512 traces * 8 channels
#define EPT 16           // elements per thread (one chunk)
#define SORT_T 256       // threads per array
#define BLOCK 512
#define CH_STRIDE 17     // padded LDS chunk stride (words) -> conflict-free b32

__device__ __forceinline__ void ce(float& a, float& b, bool up) {
    const float lo = fminf(a, b);
    const float hi = fmaxf(a, b);
    a = up ? lo : hi;
    b = up ? hi : lo;
}

// Cross-lane xor-exchange: returns partner-lane value of v for lane^M.
// M=1,2: DPP quad_perm (VALU pipe, no DS traffic).
// M=4,8,16: ds_swizzle (single DS instr, no vaddr math).
// M=32: ds_bpermute with precomputed byte address.
template <int M>
__device__ __forceinline__ float lane_xor(float v, int bperm_addr) {
    const int i = __builtin_bit_cast(int, v);
    int r;
    if constexpr (M == 1) {
        r = __builtin_amdgcn_update_dpp(i, i, 0xB1, 0xF, 0xF, true); // quad_perm [1,0,3,2]
    } else if constexpr (M == 2) {
        r = __builtin_amdgcn_update_dpp(i, i, 0x4E, 0xF, 0xF, true); // quad_perm [2,3,0,1]
    } else if constexpr (M == 4) {
        r = __builtin_amdgcn_ds_swizzle(i, 0x101F);                  // xor 4
    } else if constexpr (M == 8) {
        r = __builtin_amdgcn_ds_swizzle(i, 0x201F);                  // xor 8
    } else if constexpr (M == 16) {
        r = __builtin_amdgcn_ds_swizzle(i, 0x401F);                  // xor 16
    } else {
        r = __builtin_amdgcn_ds_bpermute(bperm_addr, i);             // xor 32
    }
    return __builtin_bit_cast(float, r);
}

template <int M>
__device__ __forceinline__ void xstage(float (&x)[EPT], bool keep_min, int bperm_addr) {
    #pragma unroll
    for (int e = 0; e < EPT; ++e) {
        const float y = lane_xor<M>(x[e], bperm_addr);
        x[e] = keep_min ? fminf(x[e], y) : fmaxf(x[e], y);
    }
}

__global__ __launch_bounds__(512) void wass_kernel(const float* __restrict__ pred,
                                                   const float* __restrict__ obs,
                                                   float* __restrict__ out) {
    __shared__ float lsA[SORT_T * CH_STRIDE];   // pred half
    __shared__ float lsB[SORT_T * CH_STRIDE];   // obs half
    __shared__ float red[BLOCK / 64];

    const int bid = blockIdx.x;
    const int col = (bid & 7) * 512 + (bid >> 3);  // XCD-band swizzle

    const int t   = threadIdx.x;
    const int arr = t >> 8;          // 0 = pred, 1 = obs (wave-uniform)
    const int c   = t & 255;         // chunk index within the array
    const float* __restrict__ src = arr ? obs : pred;
    float* ls = arr ? lsB : lsA;     // wave-uniform pointer

    const int lane = t & 63;
    const int bperm_addr = ((lane ^ 32) << 2);   // ds_bpermute byte addr, hoisted

    const int gbase = c * EPT;       // first global element index of my chunk

    // ---- load 16 elements of my column chunk ----
    float x[EPT];
    #pragma unroll
    for (int e = 0; e < EPT; ++e)
        x[e] = src[(size_t)(gbase + e) * NCOL + col];

    // ---- phase 1: k = 2..16, all pairs intra-thread (registers only) ----
    #pragma unroll
    for (int k = 2; k <= 16; k <<= 1) {
        #pragma unroll
        for (int j = k >> 1; j > 0; j >>= 1) {
            #pragma unroll
            for (int e = 0; e < EPT; ++e) {
                if ((e & j) == 0) {
                    const bool up = (((gbase + e) & k) == 0);
                    ce(x[e], x[e | j], up);
                }
            }
        }
    }

    // ---- phase 2: k = 32..4096 ----
    #pragma unroll
    for (int k = 32; k <= NT; k <<= 1) {
        const bool d_up = ((gbase & k) == 0);       // per-lane direction, fixed per k
        #pragma unroll
        for (int j = k >> 1; j >= EPT; j >>= 1) {
            const int m = j >> 4;                   // chunk xor distance
            const bool keep_min = (((c & m) == 0) == d_up);
            if (m <= 32) {
                switch (m) {
                    case 1:  xstage<1>(x, keep_min, bperm_addr); break;
                    case 2:  xstage<2>(x, keep_min, bperm_addr); break;
                    case 4:  xstage<4>(x, keep_min, bperm_addr); break;
                    case 8:  xstage<8>(x, keep_min, bperm_addr); break;
                    case 16: xstage<16>(x, keep_min, bperm_addr); break;
                    default: xstage<32>(x, keep_min, bperm_addr); break;
                }
            } else {
                // cross-wave (m = 64, 128): LDS round-trip
                #pragma unroll
                for (int e = 0; e < EPT; ++e)
                    ls[c * CH_STRIDE + e] = x[e];
                __syncthreads();
                const int pc = c ^ m;
                #pragma unroll
                for (int e = 0; e < EPT; ++e) {
                    const float y = ls[pc * CH_STRIDE + e];
                    x[e] = keep_min ? fminf(x[e], y) : fmaxf(x[e], y);
                }
                __syncthreads();
            }
        }
        // local tail j = 8..1 (intra-thread); direction is d_up for all e
        #pragma unroll
        for (int j = 8; j > 0; j >>= 1) {
            #pragma unroll
            for (int e = 0; e < EPT; ++e) {
                if ((e & j) == 0) ce(x[e], x[e | j], d_up);
            }
        }
    }

    // ---- epilogue: both sorted arrays -> LDS, abs-diff, block reduce ----
    #pragma unroll
    for (int e = 0; e < EPT; ++e)
        ls[c * CH_STRIDE + e] = x[e];
    __syncthreads();

    float s = 0.0f;
    #pragma unroll
    for (int q = 0; q < NT / BLOCK; ++q) {
        const int g = t * (NT / BLOCK) + q;
        const int w = (g >> 4) * CH_STRIDE + (g & 15);
        s += fabsf(lsA[w] - lsB[w]);
    }
    #pragma unroll
    for (int off = 32; off > 0; off >>= 1)
        s += __shfl_down(s, off, 64);
    if ((t & 63) == 0) red[t >> 6] = s;
    __syncthreads();
    if (t == 0) {
        float tot = 0.0f;
        #pragma unroll
        for (int w = 0; w < BLOCK / 64; ++w) tot += red[w];
        atomicAdd(out, tot * (1.0f / ((float)NT * (float)NCOL)));
    }
}

extern "C" void kernel_launch(void* const* d_in, const int* in_sizes, int n_in,
                              void* d_out, int out_size, void* d_ws, size_t ws_size,
                              hipStream_t stream) {
    const float* pred = (const float*)d_in[0];
    const float* obs  = (const float*)d_in[1];
    float* out = (float*)d_out;
    hipMemsetAsync(out, 0, sizeof(float), stream);
    wass_kernel<<<NCOL, BLOCK, 0, stream>>>(pred, obs, out);
}

// Round 4
// 307.539 us; speedup vs baseline: 2.2927x; 1.0312x over previous
//
#include <hip/hip_runtime.h>

#define NT 4096          // time samples per column
#define NCOL 4096        // 512 traces * 8 channels
#define EPT 16           // elements per thread (one chunk)
#define SORT_T 256       // threads (chunks) per array
#define BLOCK 512

__device__ __forceinline__ float b2f(int i) { return __builtin_bit_cast(float, i); }
__device__ __forceinline__ int   f2b(float f) { return __builtin_bit_cast(int, f); }

// Cross-lane fetch of partner lane^XM's value. XM in {1,2,3}: DPP quad_perm
// (VALU pipe). XM in {4,7,8,15,16,31}: ds_swizzle BitMode xor (DS pipe, no
// vaddr math). XM in {32,63}: ds_bpermute.
template <int XM>
__device__ __forceinline__ float lx(float v) {
    const int i = f2b(v);
    int r;
    if constexpr (XM == 1)       r = __builtin_amdgcn_update_dpp(0, i, 0xB1, 0xF, 0xF, true); // [1,0,3,2]
    else if constexpr (XM == 2)  r = __builtin_amdgcn_update_dpp(0, i, 0x4E, 0xF, 0xF, true); // [2,3,0,1]
    else if constexpr (XM == 3)  r = __builtin_amdgcn_update_dpp(0, i, 0x1B, 0xF, 0xF, true); // [3,2,1,0]
    else if constexpr (XM == 4)  r = __builtin_amdgcn_ds_swizzle(i, 0x101F);
    else if constexpr (XM == 7)  r = __builtin_amdgcn_ds_swizzle(i, 0x1C1F);
    else if constexpr (XM == 8)  r = __builtin_amdgcn_ds_swizzle(i, 0x201F);
    else if constexpr (XM == 15) r = __builtin_amdgcn_ds_swizzle(i, 0x3C1F);
    else if constexpr (XM == 16) r = __builtin_amdgcn_ds_swizzle(i, 0x401F);
    else if constexpr (XM == 31) r = __builtin_amdgcn_ds_swizzle(i, 0x7C1F);
    else {
        const int lane = (int)(threadIdx.x & 63);
        r = __builtin_amdgcn_ds_bpermute((lane ^ XM) << 2, i);
    }
    return b2f(r);
}

// compile-time ascending compare-exchange
__device__ __forceinline__ void cemin(float& a, float& b) {
    const float lo = fminf(a, b);
    const float hi = fmaxf(a, b);
    a = lo; b = hi;
}

// intra-thread plain stages j = 8..1 (ascending)
__device__ __forceinline__ void tail8(float (&x)[EPT]) {
    #pragma unroll
    for (int j = 8; j >= 1; j >>= 1) {
        #pragma unroll
        for (int e = 0; e < EPT; ++e)
            if ((e & j) == 0) cemin(x[e], x[e | j]);
    }
}

// normalized-bitonic reversal stage over a region of C chunks (C<=64, in-wave):
// partner chunk = c ^ (C-1), element pairing e <-> 15-e.
template <int C>
__device__ __forceinline__ void rev_wave(float (&x)[EPT], int c) {
    const bool keep_min = (c & (C >> 1)) == 0;
    float y[EPT];
    #pragma unroll
    for (int e = 0; e < EPT; ++e) y[e] = lx<C - 1>(x[EPT - 1 - e]);
    #pragma unroll
    for (int e = 0; e < EPT; ++e)
        x[e] = keep_min ? fminf(x[e], y[e]) : fmaxf(x[e], y[e]);
}

// plain cross-lane stage, chunk-xor distance M (in-wave, M<=32)
template <int M>
__device__ __forceinline__ void plain_wave(float (&x)[EPT], int c) {
    const bool keep_min = (c & M) == 0;
    #pragma unroll
    for (int e = 0; e < EPT; ++e) {
        const float y = lx<M>(x[e]);
        x[e] = keep_min ? fminf(x[e], y) : fmaxf(x[e], y);
    }
}

// cross-wave stage via LDS (b128): REV -> reversal over C chunks, else plain xor C
template <int C, bool REV>
__device__ __forceinline__ void lds_stage(float (&x)[EPT], int c, float4* ls4) {
    #pragma unroll
    for (int q = 0; q < 4; ++q)
        ls4[c * 4 + q] = make_float4(x[4 * q], x[4 * q + 1], x[4 * q + 2], x[4 * q + 3]);
    __syncthreads();
    const int  pc       = REV ? (c ^ (C - 1)) : (c ^ C);
    const bool keep_min = REV ? ((c & (C >> 1)) == 0) : ((c & C) == 0);
    float4 p[4];
    #pragma unroll
    for (int q = 0; q < 4; ++q) p[q] = ls4[pc * 4 + q];
    const float* pw = (const float*)p;   // registers; constant indices below
    #pragma unroll
    for (int e = 0; e < EPT; ++e) {
        const float y = REV ? pw[EPT - 1 - e] : pw[e];
        x[e] = keep_min ? fminf(x[e], y) : fmaxf(x[e], y);
    }
    __syncthreads();
}

__global__ __launch_bounds__(512) void wass_kernel(const float* __restrict__ pred,
                                                   const float* __restrict__ obs,
                                                   float* __restrict__ out) {
    __shared__ float4 lsA4[SORT_T * 4];   // 16 KB
    __shared__ float4 lsB4[SORT_T * 4];   // 16 KB
    __shared__ float  red[BLOCK / 64];

    const int bid = blockIdx.x;
    const int col = (bid & 7) * 512 + (bid >> 3);  // XCD-band swizzle

    const int t   = threadIdx.x;
    const int arr = t >> 8;          // 0 = pred, 1 = obs (wave-uniform)
    const int c   = t & 255;         // chunk index within the array
    const float* __restrict__ src = arr ? obs : pred;
    float4* ls4 = arr ? lsB4 : lsA4; // wave-uniform

    const int gbase = c * EPT;

    // ---- load 16 elements of my column chunk ----
    float x[EPT];
    #pragma unroll
    for (int e = 0; e < EPT; ++e)
        x[e] = src[(size_t)(gbase + e) * NCOL + col];

    // ---- phase 1: normalized bitonic 16-sort, fully in registers,
    //      every CE compile-time ascending ----
    #pragma unroll
    for (int kk = 2; kk <= 16; kk <<= 1) {
        #pragma unroll
        for (int b = 0; b < EPT; b += kk) {
            #pragma unroll
            for (int e = 0; e < kk / 2; ++e)
                cemin(x[b + e], x[b + kk - 1 - e]);
        }
        #pragma unroll
        for (int j = kk / 4; j >= 1; j >>= 1) {
            #pragma unroll
            for (int e = 0; e < EPT; ++e)
                if ((e & j) == 0) cemin(x[e], x[e | j]);
        }
    }

    // ---- phase 2: normalized bitonic merges k = 32 .. 4096 ----
    // k=32
    rev_wave<2>(x, c);  tail8(x);
    // k=64
    rev_wave<4>(x, c);  plain_wave<1>(x, c); tail8(x);
    // k=128
    rev_wave<8>(x, c);  plain_wave<2>(x, c); plain_wave<1>(x, c); tail8(x);
    // k=256
    rev_wave<16>(x, c); plain_wave<4>(x, c); plain_wave<2>(x, c); plain_wave<1>(x, c); tail8(x);
    // k=512
    rev_wave<32>(x, c); plain_wave<8>(x, c); plain_wave<4>(x, c); plain_wave<2>(x, c);
    plain_wave<1>(x, c); tail8(x);
    // k=1024
    rev_wave<64>(x, c); plain_wave<16>(x, c); plain_wave<8>(x, c); plain_wave<4>(x, c);
    plain_wave<2>(x, c); plain_wave<1>(x, c); tail8(x);
    // k=2048
    lds_stage<128, true>(x, c, ls4);
    plain_wave<32>(x, c); plain_wave<16>(x, c); plain_wave<8>(x, c); plain_wave<4>(x, c);
    plain_wave<2>(x, c); plain_wave<1>(x, c); tail8(x);
    // k=4096
    lds_stage<256, true>(x, c, ls4);
    lds_stage<64, false>(x, c, ls4);
    plain_wave<32>(x, c); plain_wave<16>(x, c); plain_wave<8>(x, c); plain_wave<4>(x, c);
    plain_wave<2>(x, c); plain_wave<1>(x, c); tail8(x);

    // ---- epilogue: both sorted arrays -> LDS (b128), abs-diff, block reduce ----
    #pragma unroll
    for (int q = 0; q < 4; ++q)
        ls4[c * 4 + q] = make_float4(x[4 * q], x[4 * q + 1], x[4 * q + 2], x[4 * q + 3]);
    __syncthreads();

    float s = 0.0f;
    {
        const float4 a0 = lsA4[t * 2],     b0 = lsB4[t * 2];
        const float4 a1 = lsA4[t * 2 + 1], b1 = lsB4[t * 2 + 1];
        s = fabsf(a0.x - b0.x) + fabsf(a0.y - b0.y) + fabsf(a0.z - b0.z) + fabsf(a0.w - b0.w)
          + fabsf(a1.x - b1.x) + fabsf(a1.y - b1.y) + fabsf(a1.z - b1.z) + fabsf(a1.w - b1.w);
    }
    #pragma unroll
    for (int off = 32; off > 0; off >>= 1)
        s += __shfl_down(s, off, 64);
    if ((t & 63) == 0) red[t >> 6] = s;
    __syncthreads();
    if (t == 0) {
        float tot = 0.0f;
        #pragma unroll
        for (int w = 0; w < BLOCK / 64; ++w) tot += red[w];
        atomicAdd(out, tot * (1.0f / ((float)NT * (float)NCOL)));
    }
}

extern "C" void kernel_launch(void* const* d_in, const int* in_sizes, int n_in,
                              void* d_out, int out_size, void* d_ws, size_t ws_size,
                              hipStream_t stream) {
    const float* pred = (const float*)d_in[0];
    const float* obs  = (const float*)d_in[1];
    float* out = (float*)d_out;
    hipMemsetAsync(out, 0, sizeof(float), stream);
    wass_kernel<<<NCOL, BLOCK, 0, stream>>>(pred, obs, out);
}

// Round 5
// 298.373 us; speedup vs baseline: 2.3632x; 1.0307x over previous
//
#include <hip/hip_runtime.h>

#define NT 4096          // time samples per column
#define NCOL 4096        // 512 traces * 8 channels
#define EPT 16           // elements per thread (one chunk)
#define SORT_T 256       // threads (chunks) per array
#define BLOCK 512

__device__ __forceinline__ float b2f(int i) { return __builtin_bit_cast(float, i); }
__device__ __forceinline__ int   f2b(float f) { return __builtin_bit_cast(int, f); }

// Bank-conflict-free float4 slot for (chunk c, quarter q): rotate q by c>>1 so a
// wave's b128 ops cover all 8 bank-groups (2-way aliasing = free, m136).
__device__ __forceinline__ int slot(int c, int q) { return c * 4 + ((q + (c >> 1)) & 3); }

// Cross-lane fetch of partner lane^XM's value.
// XM 1,2,3: DPP quad_perm; XM 7: DPP row_half_mirror; XM 15: DPP row_mirror
// (all VALU pipe). XM 4,8,16,31: ds_swizzle BitMode xor. XM 32,63: ds_bpermute.
template <int XM>
__device__ __forceinline__ float lx(float v) {
    const int i = f2b(v);
    int r;
    if constexpr (XM == 1)       r = __builtin_amdgcn_update_dpp(0, i, 0xB1,  0xF, 0xF, true); // [1,0,3,2]
    else if constexpr (XM == 2)  r = __builtin_amdgcn_update_dpp(0, i, 0x4E,  0xF, 0xF, true); // [2,3,0,1]
    else if constexpr (XM == 3)  r = __builtin_amdgcn_update_dpp(0, i, 0x1B,  0xF, 0xF, true); // [3,2,1,0]
    else if constexpr (XM == 7)  r = __builtin_amdgcn_update_dpp(0, i, 0x141, 0xF, 0xF, true); // row_half_mirror = lane^7
    else if constexpr (XM == 15) r = __builtin_amdgcn_update_dpp(0, i, 0x140, 0xF, 0xF, true); // row_mirror = lane^15
    else if constexpr (XM == 4)  r = __builtin_amdgcn_ds_swizzle(i, 0x101F);
    else if constexpr (XM == 8)  r = __builtin_amdgcn_ds_swizzle(i, 0x201F);
    else if constexpr (XM == 16) r = __builtin_amdgcn_ds_swizzle(i, 0x401F);
    else if constexpr (XM == 31) r = __builtin_amdgcn_ds_swizzle(i, 0x7C1F);
    else {
        const int lane = (int)(threadIdx.x & 63);
        r = __builtin_amdgcn_ds_bpermute((lane ^ XM) << 2, i);
    }
    return b2f(r);
}

// compile-time ascending compare-exchange
__device__ __forceinline__ void cemin(float& a, float& b) {
    const float lo = fminf(a, b);
    const float hi = fmaxf(a, b);
    a = lo; b = hi;
}

// intra-thread plain stages j = 8..1 (ascending)
__device__ __forceinline__ void tail8(float (&x)[EPT]) {
    #pragma unroll
    for (int j = 8; j >= 1; j >>= 1) {
        #pragma unroll
        for (int e = 0; e < EPT; ++e)
            if ((e & j) == 0) cemin(x[e], x[e | j]);
    }
}

// normalized-bitonic reversal stage over C chunks (C<=64, in-wave):
// partner chunk = c ^ (C-1), element pairing e <-> 15-e.
template <int C>
__device__ __forceinline__ void rev_wave(float (&x)[EPT], int c) {
    const bool keep_min = (c & (C >> 1)) == 0;
    float y[EPT];
    #pragma unroll
    for (int e = 0; e < EPT; ++e) y[e] = lx<C - 1>(x[EPT - 1 - e]);
    #pragma unroll
    for (int e = 0; e < EPT; ++e)
        x[e] = keep_min ? fminf(x[e], y[e]) : fmaxf(x[e], y[e]);
}

// plain cross-lane stage, chunk-xor distance M (in-wave, M<=32)
template <int M>
__device__ __forceinline__ void plain_wave(float (&x)[EPT], int c) {
    const bool keep_min = (c & M) == 0;
    #pragma unroll
    for (int e = 0; e < EPT; ++e) {
        const float y = lx<M>(x[e]);
        x[e] = keep_min ? fminf(x[e], y) : fmaxf(x[e], y);
    }
}

// cross-wave stage via LDS (b128, swizzled slots): REV -> reversal over C chunks,
// else plain xor C
template <int C, bool REV>
__device__ __forceinline__ void lds_stage(float (&x)[EPT], int c, float4* ls4) {
    #pragma unroll
    for (int q = 0; q < 4; ++q)
        ls4[slot(c, q)] = make_float4(x[4 * q], x[4 * q + 1], x[4 * q + 2], x[4 * q + 3]);
    __syncthreads();
    const int  pc       = REV ? (c ^ (C - 1)) : (c ^ C);
    const bool keep_min = REV ? ((c & (C >> 1)) == 0) : ((c & C) == 0);
    float4 p[4];
    #pragma unroll
    for (int q = 0; q < 4; ++q) p[q] = ls4[slot(pc, q)];
    const float* pw = (const float*)p;   // registers; constant indices below
    #pragma unroll
    for (int e = 0; e < EPT; ++e) {
        const float y = REV ? pw[EPT - 1 - e] : pw[e];
        x[e] = keep_min ? fminf(x[e], y) : fmaxf(x[e], y);
    }
    __syncthreads();
}

__global__ __launch_bounds__(512) void wass_kernel(const float* __restrict__ pred,
                                                   const float* __restrict__ obs,
                                                   float* __restrict__ out) {
    __shared__ float4 lsA4[SORT_T * 4];   // 16 KB
    __shared__ float4 lsB4[SORT_T * 4];   // 16 KB
    __shared__ float  red[BLOCK / 64];

    const int bid = blockIdx.x;
    const int col = (bid & 7) * 512 + (bid >> 3);  // XCD-band swizzle

    const int t   = threadIdx.x;
    const int arr = t >> 8;          // 0 = pred, 1 = obs (wave-uniform)
    const int c   = t & 255;         // chunk index within the array
    const float* __restrict__ src = arr ? obs : pred;
    float4* ls4 = arr ? lsB4 : lsA4; // wave-uniform

    const int gbase = c * EPT;

    // ---- load 16 elements of my column chunk ----
    float x[EPT];
    #pragma unroll
    for (int e = 0; e < EPT; ++e)
        x[e] = src[(size_t)(gbase + e) * NCOL + col];

    // ---- phase 1: normalized bitonic 16-sort, fully in registers ----
    #pragma unroll
    for (int kk = 2; kk <= 16; kk <<= 1) {
        #pragma unroll
        for (int b = 0; b < EPT; b += kk) {
            #pragma unroll
            for (int e = 0; e < kk / 2; ++e)
                cemin(x[b + e], x[b + kk - 1 - e]);
        }
        #pragma unroll
        for (int j = kk / 4; j >= 1; j >>= 1) {
            #pragma unroll
            for (int e = 0; e < EPT; ++e)
                if ((e & j) == 0) cemin(x[e], x[e | j]);
        }
    }

    // ---- phase 2: normalized bitonic merges k = 32 .. 4096 ----
    // k=32
    rev_wave<2>(x, c);  tail8(x);
    // k=64
    rev_wave<4>(x, c);  plain_wave<1>(x, c); tail8(x);
    // k=128
    rev_wave<8>(x, c);  plain_wave<2>(x, c); plain_wave<1>(x, c); tail8(x);
    // k=256
    rev_wave<16>(x, c); plain_wave<4>(x, c); plain_wave<2>(x, c); plain_wave<1>(x, c); tail8(x);
    // k=512
    rev_wave<32>(x, c); plain_wave<8>(x, c); plain_wave<4>(x, c); plain_wave<2>(x, c);
    plain_wave<1>(x, c); tail8(x);
    // k=1024
    rev_wave<64>(x, c); plain_wave<16>(x, c); plain_wave<8>(x, c); plain_wave<4>(x, c);
    plain_wave<2>(x, c); plain_wave<1>(x, c); tail8(x);
    // k=2048
    lds_stage<128, true>(x, c, ls4);
    plain_wave<32>(x, c); plain_wave<16>(x, c); plain_wave<8>(x, c); plain_wave<4>(x, c);
    plain_wave<2>(x, c); plain_wave<1>(x, c); tail8(x);
    // k=4096
    lds_stage<256, true>(x, c, ls4);
    lds_stage<64, false>(x, c, ls4);
    plain_wave<32>(x, c); plain_wave<16>(x, c); plain_wave<8>(x, c); plain_wave<4>(x, c);
    plain_wave<2>(x, c); plain_wave<1>(x, c); tail8(x);

    // ---- epilogue: sorted arrays -> LDS (swizzled b128), abs-diff, reduce ----
    #pragma unroll
    for (int q = 0; q < 4; ++q)
        ls4[slot(c, q)] = make_float4(x[4 * q], x[4 * q + 1], x[4 * q + 2], x[4 * q + 3]);
    __syncthreads();

    // thread t handles half of chunk (t>>1): quarters 2*(t&1), 2*(t&1)+1
    float s = 0.0f;
    {
        const int ec = t >> 1;
        const int q0 = (t & 1) * 2;
        #pragma unroll
        for (int q = 0; q < 2; ++q) {
            const float4 a = lsA4[slot(ec, q0 + q)];
            const float4 b = lsB4[slot(ec, q0 + q)];
            s += fabsf(a.x - b.x) + fabsf(a.y - b.y) + fabsf(a.z - b.z) + fabsf(a.w - b.w);
        }
    }
    #pragma unroll
    for (int off = 32; off > 0; off >>= 1)
        s += __shfl_down(s, off, 64);
    if ((t & 63) == 0) red[t >> 6] = s;
    __syncthreads();
    if (t == 0) {
        float tot = 0.0f;
        #pragma unroll
        for (int w = 0; w < BLOCK / 64; ++w) tot += red[w];
        atomicAdd(out, tot * (1.0f / ((float)NT * (float)NCOL)));
    }
}

extern "C" void kernel_launch(void* const* d_in, const int* in_sizes, int n_in,
                              void* d_out, int out_size, void* d_ws, size_t ws_size,
                              hipStream_t stream) {
    const float* pred = (const float*)d_in[0];
    const float* obs  = (const float*)d_in[1];
    float* out = (float*)d_out;
    hipMemsetAsync(out, 0, sizeof(float), stream);
    wass_kernel<<<NCOL, BLOCK, 0, stream>>>(pred, obs, out);
}